// Round 1
// baseline (828.131 us; speedup 1.0000x reference)
//
#include <hip/hip_runtime.h>
#include <hip/hip_bf16.h>

#define N_NODES 50000
#define N_EDGES 400000
#define DIM     128
#define NREL    8
#define NBASES  4

typedef __hip_bfloat16 bf16;

// ---- workspace layout (bytes) ----
// Hr  bf16 [NREL][N_NODES][DIM] : 8*50000*128*2 = 102,400,000
// agg f32  [N_NODES][DIM]       : 25,600,000
// Wr  f32  [NREL][DIM][DIM]     : 524,288
// fwT f32  [DIM][DIM]           : 65,536
#define HR_OFF   0
#define AGG_OFF  102400000LL
#define WR_OFF   128000000LL
#define FWT_OFF  128524288LL
#define WS_NEEDED 128589824LL

// ---------------------------------------------------------------------------
// K_prep: Wr[r] = sum_b w_comp[r,b] * V[b]  (fp32), and fwT = ffn_w^T
__global__ __launch_bounds__(256)
void k_prep(const float* __restrict__ V, const float* __restrict__ wc,
            const float* __restrict__ ffn_w, float* __restrict__ Wr,
            float* __restrict__ fwT) {
    int p = blockIdx.x * 256 + threadIdx.x;
    if (p < NREL * DIM * DIM) {
        int r = p >> 14;          // /16384
        int rem = p & 16383;      // i*128+o
        float acc = 0.f;
#pragma unroll
        for (int b = 0; b < NBASES; ++b)
            acc += wc[r * NBASES + b] * V[b * DIM * DIM + rem];
        Wr[p] = acc;
    }
    if (p < DIM * DIM) {
        int i = p >> 7, o = p & 127;
        fwT[p] = ffn_w[o * DIM + i];
    }
}

// ---------------------------------------------------------------------------
// K_zero: zero the agg buffer (float4 stores)
__global__ __launch_bounds__(256)
void k_zero(float4* __restrict__ agg4, int n4) {
    int p = blockIdx.x * 256 + threadIdx.x;
    if (p < n4) agg4[p] = float4{0.f, 0.f, 0.f, 0.f};
}

// ---------------------------------------------------------------------------
// K_gemm: Hr[r] = h @ Wr[r], write bf16. Tile: 32 nodes x 128 out, K=128.
__global__ __launch_bounds__(256)
void k_gemm(const float* __restrict__ h, const float* __restrict__ Wr,
            bf16* __restrict__ Hr) {
    __shared__ float w_lds[DIM * DIM];   // 64 KB
    __shared__ float h_lds[32 * DIM];    // 16 KB
    const int t = threadIdx.x;
    const int r = blockIdx.y;
    const int n0 = blockIdx.x * 32;

    const float* Wsrc = Wr + r * DIM * DIM;
#pragma unroll
    for (int k = 0; k < (DIM * DIM) / 256; ++k)
        w_lds[k * 256 + t] = Wsrc[k * 256 + t];
#pragma unroll
    for (int k = 0; k < (32 * DIM) / 256; ++k) {
        int flat = k * 256 + t;
        int row = flat >> 7, col = flat & 127;
        int n = n0 + row;
        h_lds[flat] = (n < N_NODES) ? h[(long long)n * DIM + col] : 0.f;
    }
    __syncthreads();

    const int o = t & 127, nh = t >> 7;
    float acc[16];
#pragma unroll
    for (int j = 0; j < 16; ++j) acc[j] = 0.f;

    for (int i = 0; i < DIM; i += 4) {
        float w0 = w_lds[(i + 0) * DIM + o];
        float w1 = w_lds[(i + 1) * DIM + o];
        float w2 = w_lds[(i + 2) * DIM + o];
        float w3 = w_lds[(i + 3) * DIM + o];
#pragma unroll
        for (int j = 0; j < 16; ++j) {
            const float4 hv = *(const float4*)&h_lds[(nh * 16 + j) * DIM + i];
            acc[j] = fmaf(hv.x, w0, fmaf(hv.y, w1,
                     fmaf(hv.z, w2, fmaf(hv.w, w3, acc[j]))));
        }
    }

#pragma unroll
    for (int j = 0; j < 16; ++j) {
        int n = n0 + nh * 16 + j;
        if (n < N_NODES)
            Hr[((long long)r * N_NODES + n) * DIM + o] = __float2bfloat16(acc[j]);
    }
}

// ---------------------------------------------------------------------------
// K_edge: one wave per edge; gather Hr[etype][src], scale by norm,
// atomicAdd into agg[dst].
__global__ __launch_bounds__(256)
void k_edge(const bf16* __restrict__ Hr, const int* __restrict__ src,
            const int* __restrict__ dst, const int* __restrict__ et,
            const float* __restrict__ norm, float* __restrict__ agg) {
    const int wv = threadIdx.x >> 6;
    const int l  = threadIdx.x & 63;
    const int e  = blockIdx.x * 4 + wv;
    if (e >= N_EDGES) return;
    const int s = src[e], d = dst[e], r = et[e];
    const float w = norm[e];
    const __hip_bfloat162* row =
        (const __hip_bfloat162*)(Hr + ((long long)r * N_NODES + s) * DIM);
    float2 f = __bfloat1622float2(row[l]);
    float* ap = agg + (long long)d * DIM + 2 * l;
    atomicAdd(ap,     f.x * w);
    atomicAdd(ap + 1, f.y * w);
}

// ---------------------------------------------------------------------------
// K_final: per node row: hn = relu(agg + h@loop_w + bias);
//          y = hn@ffn_w^T + ffn_b + h; out = LayerNorm(y)*g + b.
// Block = 128 threads (thread o = output column), 8 nodes per iteration.
__global__ __launch_bounds__(128)
void k_final(const float* __restrict__ h, const float* __restrict__ agg,
             const float* __restrict__ loop_w, const float* __restrict__ bias,
             const float* __restrict__ fwT, const float* __restrict__ ffn_b,
             const float* __restrict__ ln_g, const float* __restrict__ ln_b,
             float* __restrict__ out) {
    __shared__ float hrow[8][DIM];
    __shared__ float hn[8][DIM];
    __shared__ float red[2][8][2];
    const int o = threadIdx.x;        // 0..127
    const int wv = o >> 6, l = o & 63;
    const float bo = bias[o];
    const float fb = ffn_b[o];
    const float g  = ln_g[o];
    const float bb = ln_b[o];

    for (long long base = (long long)blockIdx.x * 8; base < N_NODES;
         base += (long long)gridDim.x * 8) {
        const int nn = (int)min(8LL, (long long)N_NODES - base);
        for (int j = 0; j < nn; ++j)
            hrow[j][o] = h[(base + j) * DIM + o];
        __syncthreads();

        // stage 1: acc1 = h @ loop_w
        float acc1[8];
#pragma unroll
        for (int j = 0; j < 8; ++j) acc1[j] = 0.f;
        for (int i = 0; i < DIM; i += 4) {
            float w0 = loop_w[(i + 0) * DIM + o];
            float w1 = loop_w[(i + 1) * DIM + o];
            float w2 = loop_w[(i + 2) * DIM + o];
            float w3 = loop_w[(i + 3) * DIM + o];
#pragma unroll
            for (int j = 0; j < 8; ++j) {
                const float4 hv = *(const float4*)&hrow[j][i];
                acc1[j] = fmaf(hv.x, w0, fmaf(hv.y, w1,
                          fmaf(hv.z, w2, fmaf(hv.w, w3, acc1[j]))));
            }
        }
        for (int j = 0; j < nn; ++j) {
            float v = acc1[j] + agg[(base + j) * DIM + o] + bo;
            hn[j][o] = fmaxf(v, 0.f);
        }
        __syncthreads();

        // stage 2: acc2 = hn @ ffn_w^T  (fwT[i][o] = ffn_w[o][i])
        float acc2[8];
#pragma unroll
        for (int j = 0; j < 8; ++j) acc2[j] = 0.f;
        for (int i = 0; i < DIM; i += 4) {
            float w0 = fwT[(i + 0) * DIM + o];
            float w1 = fwT[(i + 1) * DIM + o];
            float w2 = fwT[(i + 2) * DIM + o];
            float w3 = fwT[(i + 3) * DIM + o];
#pragma unroll
            for (int j = 0; j < 8; ++j) {
                const float4 hv = *(const float4*)&hn[j][i];
                acc2[j] = fmaf(hv.x, w0, fmaf(hv.y, w1,
                          fmaf(hv.z, w2, fmaf(hv.w, w3, acc2[j]))));
            }
        }

        // y, then LayerNorm (wave shuffle reduce + cross-wave via LDS)
        for (int j = 0; j < nn; ++j) {
            float y = acc2[j] + fb + hrow[j][o];
            acc2[j] = y;
            float s = y, s2 = y * y;
#pragma unroll
            for (int m = 1; m < 64; m <<= 1) {
                s  += __shfl_xor(s, m);
                s2 += __shfl_xor(s2, m);
            }
            if (l == 0) { red[wv][j][0] = s; red[wv][j][1] = s2; }
        }
        __syncthreads();
        for (int j = 0; j < nn; ++j) {
            float S  = red[0][j][0] + red[1][j][0];
            float S2 = red[0][j][1] + red[1][j][1];
            float mu  = S * (1.f / DIM);
            float var = S2 * (1.f / DIM) - mu * mu;
            float inv = rsqrtf(var + 1e-8f);
            out[(base + j) * DIM + o] = (acc2[j] - mu) * inv * g + bb;
        }
        __syncthreads();
    }
}

// ---------------------------------------------------------------------------
extern "C" void kernel_launch(void* const* d_in, const int* in_sizes, int n_in,
                              void* d_out, int out_size, void* d_ws, size_t ws_size,
                              hipStream_t stream) {
    const float* h      = (const float*)d_in[0];
    const float* V      = (const float*)d_in[1];
    const float* w_comp = (const float*)d_in[2];
    const float* loop_w = (const float*)d_in[3];
    const float* bias   = (const float*)d_in[4];
    const float* ffn_w  = (const float*)d_in[5];
    const float* ffn_b  = (const float*)d_in[6];
    const float* ln_g   = (const float*)d_in[7];
    const float* ln_b   = (const float*)d_in[8];
    const float* norm   = (const float*)d_in[9];
    const int*   src    = (const int*)d_in[10];
    const int*   dst    = (const int*)d_in[11];
    const int*   etype  = (const int*)d_in[12];
    float* out = (float*)d_out;

    if (ws_size < (size_t)WS_NEEDED) return;  // fail visibly rather than corrupt

    char* ws = (char*)d_ws;
    bf16*  Hr  = (bf16*)(ws + HR_OFF);
    float* agg = (float*)(ws + AGG_OFF);
    float* Wr  = (float*)(ws + WR_OFF);
    float* fwT = (float*)(ws + FWT_OFF);

    // 1. per-relation weights + ffn_w transpose
    k_prep<<<dim3((NREL * DIM * DIM + 255) / 256), dim3(256), 0, stream>>>(
        V, w_comp, ffn_w, Wr, fwT);

    // 2. zero agg
    k_zero<<<dim3((N_NODES * DIM / 4 + 255) / 256), dim3(256), 0, stream>>>(
        (float4*)agg, N_NODES * DIM / 4);

    // 3. Hr[r] = h @ Wr[r]
    k_gemm<<<dim3((N_NODES + 31) / 32, NREL), dim3(256), 0, stream>>>(h, Wr, Hr);

    // 4. edge gather + scatter-add
    k_edge<<<dim3(N_EDGES / 4), dim3(256), 0, stream>>>(Hr, src, dst, etype, norm, agg);

    // 5. fused self-loop + relu + ffn + residual + layernorm
    k_final<<<dim3(2048), dim3(128), 0, stream>>>(
        h, agg, loop_w, bias, fwT, ffn_b, ln_g, ln_b, out);
}

// Round 2
// 520.143 us; speedup vs baseline: 1.5921x; 1.5921x over previous
//
#include <hip/hip_runtime.h>
#include <hip/hip_bf16.h>

#define N_NODES 50000
#define N_EDGES 400000
#define DIM     128
#define NREL    8
#define NBASES  4

typedef __hip_bfloat16 bf16;

typedef __bf16 bf16x8 __attribute__((ext_vector_type(8)));
typedef float  f32x4  __attribute__((ext_vector_type(4)));

union frag_u { bf16x8 v; bf16 e[8]; };

// ---- workspace layout (bytes) ----
// Hr   bf16 [NREL][N_NODES][DIM] : 102,400,000
// agg  f32  [N_NODES][DIM]       :  25,600,000
// WrT  bf16 [NREL][DIM][DIM]     :     262,144   (WrT[r][o][i] = W_r[i][o])
// fwT  f32  [DIM][DIM]           :      65,536
#define HR_OFF   0
#define AGG_OFF  102400000LL
#define WRT_OFF  128000000LL
#define FWT_OFF  128262144LL
#define WS_NEEDED 128327680LL

// ---------------------------------------------------------------------------
// K_prep: WrT[r][o][i] = bf16( sum_b w_comp[r,b] * V[b][i][o] ), fwT = ffn_w^T
__global__ __launch_bounds__(256)
void k_prep(const float* __restrict__ V, const float* __restrict__ wc,
            const float* __restrict__ ffn_w, bf16* __restrict__ WrT,
            float* __restrict__ fwT) {
    int p = blockIdx.x * 256 + threadIdx.x;
    if (p < NREL * DIM * DIM) {
        int r = p >> 14;          // /16384
        int rem = p & 16383;      // i*128+o
        int i = rem >> 7, o = rem & 127;
        float acc = 0.f;
#pragma unroll
        for (int b = 0; b < NBASES; ++b)
            acc += wc[r * NBASES + b] * V[b * DIM * DIM + rem];
        WrT[r * DIM * DIM + o * DIM + i] = __float2bfloat16(acc);
    }
    if (p < DIM * DIM) {
        int i = p >> 7, o = p & 127;
        fwT[p] = ffn_w[o * DIM + i];
    }
}

// ---------------------------------------------------------------------------
// K_zero: zero the agg buffer (float4 stores)
__global__ __launch_bounds__(256)
void k_zero(float4* __restrict__ agg4, int n4) {
    int p = blockIdx.x * 256 + threadIdx.x;
    if (p < n4) agg4[p] = float4{0.f, 0.f, 0.f, 0.f};
}

// ---------------------------------------------------------------------------
// K_gemm (MFMA): Hr[r] = bf16( h @ W_r ).
// Block: 256 thr = 4 waves; tile 128 rows x 128 cols. Wave w owns rows
// [n0+32w, n0+32w+32). Register-resident: no LDS. A loaded f32->bf16 from h,
// B loaded bf16 from WrT (k-contiguous). 64 MFMAs (16x16x32) per wave.
__global__ __launch_bounds__(256)
void k_gemm(const float* __restrict__ h, const bf16* __restrict__ WrT,
            bf16* __restrict__ Hr) {
    const int t   = threadIdx.x;
    const int wid = t >> 6;
    const int l   = t & 63;
    const int r   = blockIdx.y;
    const int n0  = blockIdx.x * 128;

    const int lrow = l & 15;        // A row / B col within 16-tile
    const int kgrp = l >> 4;        // k sub-group (8 elems each)

    const bf16* Bsrc = WrT + r * DIM * DIM;

    f32x4 acc[2][8];
#pragma unroll
    for (int mt = 0; mt < 2; ++mt)
#pragma unroll
        for (int nt = 0; nt < 8; ++nt)
            acc[mt][nt] = f32x4{0.f, 0.f, 0.f, 0.f};

#pragma unroll 1
    for (int ks = 0; ks < 4; ++ks) {
        const int k0 = ks * 32 + kgrp * 8;

        // A fragments: rows n0+32w+16mt+lrow, k = k0..k0+7 (f32 -> bf16)
        frag_u a[2];
#pragma unroll
        for (int mt = 0; mt < 2; ++mt) {
            int row = n0 + wid * 32 + mt * 16 + lrow;
            row = row < N_NODES ? row : N_NODES - 1;   // clamp (stores predicated)
            const float* hp = h + (long long)row * DIM + k0;
            const f32x4 lo = *(const f32x4*)hp;
            const f32x4 hi = *(const f32x4*)(hp + 4);
#pragma unroll
            for (int j = 0; j < 4; ++j) {
                a[mt].e[j]     = __float2bfloat16(lo[j]);
                a[mt].e[4 + j] = __float2bfloat16(hi[j]);
            }
        }

        // B fragments: WrT[col][k0..k0+7], col = 16nt + lrow
        frag_u b[8];
#pragma unroll
        for (int nt = 0; nt < 8; ++nt)
            b[nt].v = *(const bf16x8*)(Bsrc + (nt * 16 + lrow) * DIM + k0);

#pragma unroll
        for (int mt = 0; mt < 2; ++mt)
#pragma unroll
            for (int nt = 0; nt < 8; ++nt)
                acc[mt][nt] = __builtin_amdgcn_mfma_f32_16x16x32_bf16(
                    a[mt].v, b[nt].v, acc[mt][nt], 0, 0, 0);
    }

    // Epilogue: C row = 4*kgrp + j, col = 16nt + lrow
    const long long obase = (long long)r * N_NODES;
#pragma unroll
    for (int mt = 0; mt < 2; ++mt) {
#pragma unroll
        for (int j = 0; j < 4; ++j) {
            const int row = n0 + wid * 32 + mt * 16 + kgrp * 4 + j;
            if (row < N_NODES) {
                bf16* op = Hr + (obase + row) * DIM + lrow;
#pragma unroll
                for (int nt = 0; nt < 8; ++nt)
                    op[nt * 16] = __float2bfloat16(acc[mt][nt][j]);
            }
        }
    }
}

// ---------------------------------------------------------------------------
// K_edge: one wave per edge; gather Hr[etype][src], scale by norm,
// atomicAdd into agg[dst].
__global__ __launch_bounds__(256)
void k_edge(const bf16* __restrict__ Hr, const int* __restrict__ src,
            const int* __restrict__ dst, const int* __restrict__ et,
            const float* __restrict__ norm, float* __restrict__ agg) {
    const int wv = threadIdx.x >> 6;
    const int l  = threadIdx.x & 63;
    const int e  = blockIdx.x * 4 + wv;
    if (e >= N_EDGES) return;
    const int s = src[e], d = dst[e], r = et[e];
    const float w = norm[e];
    const __hip_bfloat162* row =
        (const __hip_bfloat162*)(Hr + ((long long)r * N_NODES + s) * DIM);
    float2 f = __bfloat1622float2(row[l]);
    float* ap = agg + (long long)d * DIM + 2 * l;
    atomicAdd(ap,     f.x * w);
    atomicAdd(ap + 1, f.y * w);
}

// ---------------------------------------------------------------------------
// K_final: per node row: hn = relu(agg + h@loop_w + bias);
//          y = hn@ffn_w^T + ffn_b + h; out = LayerNorm(y)*g + b.
__global__ __launch_bounds__(128)
void k_final(const float* __restrict__ h, const float* __restrict__ agg,
             const float* __restrict__ loop_w, const float* __restrict__ bias,
             const float* __restrict__ fwT, const float* __restrict__ ffn_b,
             const float* __restrict__ ln_g, const float* __restrict__ ln_b,
             float* __restrict__ out) {
    __shared__ float hrow[8][DIM];
    __shared__ float hn[8][DIM];
    __shared__ float red[2][8][2];
    const int o = threadIdx.x;        // 0..127
    const int wv = o >> 6, l = o & 63;
    const float bo = bias[o];
    const float fb = ffn_b[o];
    const float g  = ln_g[o];
    const float bb = ln_b[o];

    for (long long base = (long long)blockIdx.x * 8; base < N_NODES;
         base += (long long)gridDim.x * 8) {
        const int nn = (int)min(8LL, (long long)N_NODES - base);
        for (int j = 0; j < nn; ++j)
            hrow[j][o] = h[(base + j) * DIM + o];
        __syncthreads();

        // stage 1: acc1 = h @ loop_w
        float acc1[8];
#pragma unroll
        for (int j = 0; j < 8; ++j) acc1[j] = 0.f;
        for (int i = 0; i < DIM; i += 4) {
            float w0 = loop_w[(i + 0) * DIM + o];
            float w1 = loop_w[(i + 1) * DIM + o];
            float w2 = loop_w[(i + 2) * DIM + o];
            float w3 = loop_w[(i + 3) * DIM + o];
#pragma unroll
            for (int j = 0; j < 8; ++j) {
                const float4 hv = *(const float4*)&hrow[j][i];
                acc1[j] = fmaf(hv.x, w0, fmaf(hv.y, w1,
                          fmaf(hv.z, w2, fmaf(hv.w, w3, acc1[j]))));
            }
        }
        for (int j = 0; j < nn; ++j) {
            float v = acc1[j] + agg[(base + j) * DIM + o] + bo;
            hn[j][o] = fmaxf(v, 0.f);
        }
        __syncthreads();

        // stage 2: acc2 = hn @ ffn_w^T  (fwT[i][o] = ffn_w[o][i])
        float acc2[8];
#pragma unroll
        for (int j = 0; j < 8; ++j) acc2[j] = 0.f;
        for (int i = 0; i < DIM; i += 4) {
            float w0 = fwT[(i + 0) * DIM + o];
            float w1 = fwT[(i + 1) * DIM + o];
            float w2 = fwT[(i + 2) * DIM + o];
            float w3 = fwT[(i + 3) * DIM + o];
#pragma unroll
            for (int j = 0; j < 8; ++j) {
                const float4 hv = *(const float4*)&hn[j][i];
                acc2[j] = fmaf(hv.x, w0, fmaf(hv.y, w1,
                          fmaf(hv.z, w2, fmaf(hv.w, w3, acc2[j]))));
            }
        }

        // y, then LayerNorm (wave shuffle reduce + cross-wave via LDS)
        for (int j = 0; j < nn; ++j) {
            float y = acc2[j] + fb + hrow[j][o];
            acc2[j] = y;
            float s = y, s2 = y * y;
#pragma unroll
            for (int m = 1; m < 64; m <<= 1) {
                s  += __shfl_xor(s, m);
                s2 += __shfl_xor(s2, m);
            }
            if (l == 0) { red[wv][j][0] = s; red[wv][j][1] = s2; }
        }
        __syncthreads();
        for (int j = 0; j < nn; ++j) {
            float S  = red[0][j][0] + red[1][j][0];
            float S2 = red[0][j][1] + red[1][j][1];
            float mu  = S * (1.f / DIM);
            float var = S2 * (1.f / DIM) - mu * mu;
            float inv = rsqrtf(var + 1e-8f);
            out[(base + j) * DIM + o] = (acc2[j] - mu) * inv * g + bb;
        }
        __syncthreads();
    }
}

// ---------------------------------------------------------------------------
extern "C" void kernel_launch(void* const* d_in, const int* in_sizes, int n_in,
                              void* d_out, int out_size, void* d_ws, size_t ws_size,
                              hipStream_t stream) {
    const float* h      = (const float*)d_in[0];
    const float* V      = (const float*)d_in[1];
    const float* w_comp = (const float*)d_in[2];
    const float* loop_w = (const float*)d_in[3];
    const float* bias   = (const float*)d_in[4];
    const float* ffn_w  = (const float*)d_in[5];
    const float* ffn_b  = (const float*)d_in[6];
    const float* ln_g   = (const float*)d_in[7];
    const float* ln_b   = (const float*)d_in[8];
    const float* norm   = (const float*)d_in[9];
    const int*   src    = (const int*)d_in[10];
    const int*   dst    = (const int*)d_in[11];
    const int*   etype  = (const int*)d_in[12];
    float* out = (float*)d_out;

    if (ws_size < (size_t)WS_NEEDED) return;

    char* ws = (char*)d_ws;
    bf16*  Hr  = (bf16*)(ws + HR_OFF);
    float* agg = (float*)(ws + AGG_OFF);
    bf16*  WrT = (bf16*)(ws + WRT_OFF);
    float* fwT = (float*)(ws + FWT_OFF);

    // 1. per-relation transposed bf16 weights + ffn_w transpose
    k_prep<<<dim3((NREL * DIM * DIM + 255) / 256), dim3(256), 0, stream>>>(
        V, w_comp, ffn_w, WrT, fwT);

    // 2. zero agg
    k_zero<<<dim3((N_NODES * DIM / 4 + 255) / 256), dim3(256), 0, stream>>>(
        (float4*)agg, N_NODES * DIM / 4);

    // 3. Hr[r] = h @ W_r  (MFMA)
    k_gemm<<<dim3((N_NODES + 127) / 128, NREL), dim3(256), 0, stream>>>(h, WrT, Hr);

    // 4. edge gather + scatter-add
    k_edge<<<dim3(N_EDGES / 4), dim3(256), 0, stream>>>(Hr, src, dst, etype, norm, agg);

    // 5. fused self-loop + relu + ffn + residual + layernorm
    k_final<<<dim3(2048), dim3(128), 0, stream>>>(
        h, agg, loop_w, bias, fwT, ffn_b, ln_g, ln_b, out);
}

// Round 3
// 362.484 us; speedup vs baseline: 2.2846x; 1.4349x over previous
//
#include <hip/hip_runtime.h>
#include <hip/hip_bf16.h>

#define N_NODES 50000
#define N_EDGES 400000
#define DIM     128
#define NREL    8
#define NBASES  4
#define NGROUPS (N_NODES / 8)

typedef __hip_bfloat16 bf16;

typedef __bf16 bf16x8 __attribute__((ext_vector_type(8)));
typedef float  f32x4  __attribute__((ext_vector_type(4)));

union frag_u { bf16x8 v; bf16 e[8]; };
union pack4_u { unsigned long long ll; bf16 b[4]; };

// ---- workspace layout (bytes) ----
// Hr   bf16 [NREL][N_NODES][DIM] : 102,400,000
// recs uint2 [E]                 :   3,200,000   (key=(src<<3)|et, norm bits)
// base int  [N_NODES+1]          :     200,064 (padded)
// cur  int  [N_NODES]            :     200,064 (hist -> cursor)
// WrT  bf16 [NREL][DIM][DIM]     :     262,144   (WrT[r][o][i] = W_r[i][o])
// fwT  f32  [DIM][DIM]           :      65,536
#define HR_OFF    0LL
#define RECS_OFF  102400000LL
#define BASE_OFF  105600000LL
#define CUR_OFF   105800064LL
#define WRT_OFF   106000128LL
#define FWT_OFF   106262272LL
#define WS_NEEDED 106327808LL

// ---------------------------------------------------------------------------
// K_prep: WrT[r][o][i] = bf16(sum_b wc[r,b]*V[b][i][o]); fwT = ffn_w^T;
//         zero the histogram/cursor array.
__global__ __launch_bounds__(256)
void k_prep(const float* __restrict__ V, const float* __restrict__ wc,
            const float* __restrict__ ffn_w, bf16* __restrict__ WrT,
            float* __restrict__ fwT, int* __restrict__ cur) {
    int p = blockIdx.x * 256 + threadIdx.x;
    if (p < NREL * DIM * DIM) {
        int r = p >> 14;
        int rem = p & 16383;      // i*128+o
        int i = rem >> 7, o = rem & 127;
        float acc = 0.f;
#pragma unroll
        for (int b = 0; b < NBASES; ++b)
            acc += wc[r * NBASES + b] * V[b * DIM * DIM + rem];
        WrT[r * DIM * DIM + o * DIM + i] = __float2bfloat16(acc);
    }
    if (p < DIM * DIM) {
        int i = p >> 7, o = p & 127;
        fwT[p] = ffn_w[o * DIM + i];
    }
    if (p < N_NODES) cur[p] = 0;
}

// ---------------------------------------------------------------------------
// K_hist: cur[d] = in-degree histogram
__global__ __launch_bounds__(256)
void k_hist(const int* __restrict__ dst, int* __restrict__ cur) {
    int e = blockIdx.x * 256 + threadIdx.x;
    if (e < N_EDGES) atomicAdd(&cur[dst[e]], 1);
}

// ---------------------------------------------------------------------------
// K_scan: exclusive prefix sum of cur -> base; cur <- base (cursor copy).
// Single block of 1024 threads, 49 elements per thread.
#define SCAN_C 49
__global__ __launch_bounds__(1024)
void k_scan(int* __restrict__ cur, int* __restrict__ base) {
    __shared__ int wsum[16];
    const int t = threadIdx.x, lane = t & 63, wv = t >> 6;
    int vals[SCAN_C];
    int s = 0;
    const int i0 = t * SCAN_C;
#pragma unroll
    for (int i = 0; i < SCAN_C; ++i) {
        int idx = i0 + i;
        int v = (idx < N_NODES) ? cur[idx] : 0;
        vals[i] = v;
        s += v;
    }
    int inc = s;
#pragma unroll
    for (int m = 1; m < 64; m <<= 1) {
        int u = __shfl_up(inc, m);
        if (lane >= m) inc += u;
    }
    if (lane == 63) wsum[wv] = inc;
    __syncthreads();
    if (t < 16) {
        int w = wsum[t];
        int winc = w;
#pragma unroll
        for (int m = 1; m < 16; m <<= 1) {
            int u = __shfl_up(winc, m);
            if (t >= m) winc += u;
        }
        wsum[t] = winc - w;   // exclusive wave offset
    }
    __syncthreads();
    int run = wsum[wv] + (inc - s);
#pragma unroll
    for (int i = 0; i < SCAN_C; ++i) {
        int idx = i0 + i;
        if (idx < N_NODES) {
            base[idx] = run;
            cur[idx]  = run;
            run += vals[i];
        }
    }
    if (t == 1023) base[N_NODES] = run;   // == N_EDGES
}

// ---------------------------------------------------------------------------
// K_scatter: bucket edges by dst. recs[pos] = {(src<<3)|et, bits(norm)}.
__global__ __launch_bounds__(256)
void k_scatter(const int* __restrict__ src, const int* __restrict__ dst,
               const int* __restrict__ et, const float* __restrict__ norm,
               int* __restrict__ cur, uint2* __restrict__ recs) {
    int e = blockIdx.x * 256 + threadIdx.x;
    if (e >= N_EDGES) return;
    int d = dst[e];
    int pos = atomicAdd(&cur[d], 1);
    uint2 rc;
    rc.x = ((unsigned)src[e] << 3) | (unsigned)et[e];
    rc.y = __float_as_uint(norm[e]);
    recs[pos] = rc;
}

// ---------------------------------------------------------------------------
// K_gemm v2 (MFMA): Hr[r] = bf16(h @ W_r) for r in [4*by, 4*by+4).
// Block 256 thr = 4 waves. A-tile (128 rows x 128 k) staged in LDS as bf16
// with XOR swizzle (byte ^= (row&7)<<4) -> conflict-free ds_read_b128.
// Swapped-operand MFMA: lane owns 4 consecutive C columns -> 8B stores.
__global__ __launch_bounds__(256)
void k_gemm(const float* __restrict__ h, const bf16* __restrict__ WrT,
            bf16* __restrict__ Hr) {
    __shared__ char A_lds[128 * 256];   // 32 KB: [row][128 bf16], swizzled
    const int t   = threadIdx.x;
    const int wid = t >> 6;
    const int l   = t & 63;
    const int n0  = blockIdx.x * 128;
    const int r0  = blockIdx.y * 4;

    // ---- stage A: f32 -> bf16, swizzled ----
#pragma unroll
    for (int it = 0; it < 16; ++it) {
        int u = it * 256 + t;        // f32x4 unit index in [0,4096)
        int row = u >> 5, c4 = u & 31;
        int gr = n0 + row;
        f32x4 v = (gr < N_NODES)
                      ? *(const f32x4*)(h + (long long)gr * DIM + c4 * 4)
                      : f32x4{0.f, 0.f, 0.f, 0.f};
        pack4_u p;
#pragma unroll
        for (int j = 0; j < 4; ++j) p.b[j] = __float2bfloat16(v[j]);
        int byte = row * 256 + c4 * 8;
        byte ^= (row & 7) << 4;
        *(unsigned long long*)(A_lds + byte) = p.ll;
    }
    __syncthreads();

    const int lrow = l & 15;
    const int kgrp = l >> 4;
    const int arow_base = wid * 32;

#pragma unroll 1
    for (int rel = r0; rel < r0 + 4; ++rel) {
        const bf16* Bsrc = WrT + rel * DIM * DIM;
        f32x4 acc[2][8];
#pragma unroll
        for (int mt = 0; mt < 2; ++mt)
#pragma unroll
            for (int nt = 0; nt < 8; ++nt)
                acc[mt][nt] = f32x4{0.f, 0.f, 0.f, 0.f};

#pragma unroll
        for (int ks = 0; ks < 4; ++ks) {
            frag_u a[2];
#pragma unroll
            for (int mt = 0; mt < 2; ++mt) {
                int arow = arow_base + mt * 16 + lrow;
                int byte = arow * 256 + ks * 64 + kgrp * 16;
                byte ^= (arow & 7) << 4;
                a[mt].v = *(const bf16x8*)(A_lds + byte);
            }
            frag_u b[8];
#pragma unroll
            for (int nt = 0; nt < 8; ++nt)
                b[nt].v = *(const bf16x8*)(Bsrc + (nt * 16 + lrow) * DIM +
                                           ks * 32 + kgrp * 8);
#pragma unroll
            for (int mt = 0; mt < 2; ++mt)
#pragma unroll
                for (int nt = 0; nt < 8; ++nt)
                    acc[mt][nt] = __builtin_amdgcn_mfma_f32_16x16x32_bf16(
                        b[nt].v, a[mt].v, acc[mt][nt], 0, 0, 0);
        }

        // store: lane holds C[row = n0+wid*32+mt*16+lrow][nt*16+kgrp*4 .. +3]
#pragma unroll
        for (int mt = 0; mt < 2; ++mt) {
            int row = n0 + arow_base + mt * 16 + lrow;
            if (row < N_NODES) {
                bf16* op = Hr + ((long long)rel * N_NODES + row) * DIM;
#pragma unroll
                for (int nt = 0; nt < 8; ++nt) {
                    pack4_u p;
#pragma unroll
                    for (int j = 0; j < 4; ++j)
                        p.b[j] = __float2bfloat16(acc[mt][nt][j]);
                    *(unsigned long long*)(op + nt * 16 + kgrp * 4) = p.ll;
                }
            }
        }
    }
}

// ---------------------------------------------------------------------------
// K_final (fused): per 8-node group:
//   gather: aggl[j] = sum_{e in CSR[dst=n]} norm_e * Hr[et_e][src_e]   (LDS)
//   hn = relu(aggl + h@loop_w + bias); y = hn@ffn_w^T + ffn_b + h; LayerNorm.
__global__ __launch_bounds__(128)
void k_final(const float* __restrict__ h, const bf16* __restrict__ Hr,
             const uint2* __restrict__ recs, const int* __restrict__ base,
             const float* __restrict__ loop_w, const float* __restrict__ bias,
             const float* __restrict__ fwT, const float* __restrict__ ffn_b,
             const float* __restrict__ ln_g, const float* __restrict__ ln_b,
             float* __restrict__ out) {
    __shared__ float hrow[8][DIM];
    __shared__ float hn[8][DIM];
    __shared__ float aggl[8][DIM];
    __shared__ float red[2][8][2];
    const int o = threadIdx.x;        // 0..127
    const int wv = o >> 6, l = o & 63;
    const float bo = bias[o];
    const float fb = ffn_b[o];
    const float g  = ln_g[o];
    const float bb = ln_b[o];

    for (int grp = blockIdx.x; grp < NGROUPS; grp += gridDim.x) {
        const long long nbase = (long long)grp * 8;

        // ---- CSR gather: wave wv owns nodes j = 4*wv .. 4*wv+3 ----
#pragma unroll
        for (int jj = 0; jj < 4; ++jj) {
            int j = wv * 4 + jj;
            int n = (int)nbase + j;
            int b0 = base[n], b1 = base[n + 1];
            float ax = 0.f, ay = 0.f;
            for (int i = b0; i < b1; ++i) {
                uint2 rc = recs[i];
                float w = __uint_as_float(rc.y);
                unsigned key = rc.x;
                const __hip_bfloat162* rp = (const __hip_bfloat162*)(
                    Hr + ((long long)(key & 7u) * N_NODES + (key >> 3)) * DIM);
                float2 f = __bfloat1622float2(rp[l]);
                ax = fmaf(f.x, w, ax);
                ay = fmaf(f.y, w, ay);
            }
            *(float2*)&aggl[j][2 * l] = float2{ax, ay};
        }

        for (int j = 0; j < 8; ++j)
            hrow[j][o] = h[(nbase + j) * DIM + o];
        __syncthreads();

        // stage 1: acc1 = h @ loop_w
        float acc1[8];
#pragma unroll
        for (int j = 0; j < 8; ++j) acc1[j] = 0.f;
        for (int i = 0; i < DIM; i += 4) {
            float w0 = loop_w[(i + 0) * DIM + o];
            float w1 = loop_w[(i + 1) * DIM + o];
            float w2 = loop_w[(i + 2) * DIM + o];
            float w3 = loop_w[(i + 3) * DIM + o];
#pragma unroll
            for (int j = 0; j < 8; ++j) {
                const float4 hv = *(const float4*)&hrow[j][i];
                acc1[j] = fmaf(hv.x, w0, fmaf(hv.y, w1,
                          fmaf(hv.z, w2, fmaf(hv.w, w3, acc1[j]))));
            }
        }
        for (int j = 0; j < 8; ++j) {
            float v = acc1[j] + aggl[j][o] + bo;
            hn[j][o] = fmaxf(v, 0.f);
        }
        __syncthreads();

        // stage 2: acc2 = hn @ ffn_w^T
        float acc2[8];
#pragma unroll
        for (int j = 0; j < 8; ++j) acc2[j] = 0.f;
        for (int i = 0; i < DIM; i += 4) {
            float w0 = fwT[(i + 0) * DIM + o];
            float w1 = fwT[(i + 1) * DIM + o];
            float w2 = fwT[(i + 2) * DIM + o];
            float w3 = fwT[(i + 3) * DIM + o];
#pragma unroll
            for (int j = 0; j < 8; ++j) {
                const float4 hv = *(const float4*)&hn[j][i];
                acc2[j] = fmaf(hv.x, w0, fmaf(hv.y, w1,
                          fmaf(hv.z, w2, fmaf(hv.w, w3, acc2[j]))));
            }
        }

        // y, then LayerNorm
        for (int j = 0; j < 8; ++j) {
            float y = acc2[j] + fb + hrow[j][o];
            acc2[j] = y;
            float s = y, s2 = y * y;
#pragma unroll
            for (int m = 1; m < 64; m <<= 1) {
                s  += __shfl_xor(s, m);
                s2 += __shfl_xor(s2, m);
            }
            if (l == 0) { red[wv][j][0] = s; red[wv][j][1] = s2; }
        }
        __syncthreads();
        for (int j = 0; j < 8; ++j) {
            float S  = red[0][j][0] + red[1][j][0];
            float S2 = red[0][j][1] + red[1][j][1];
            float mu  = S * (1.f / DIM);
            float var = S2 * (1.f / DIM) - mu * mu;
            float inv = rsqrtf(var + 1e-8f);
            out[(nbase + j) * DIM + o] = (acc2[j] - mu) * inv * g + bb;
        }
        __syncthreads();
    }
}

// ---------------------------------------------------------------------------
extern "C" void kernel_launch(void* const* d_in, const int* in_sizes, int n_in,
                              void* d_out, int out_size, void* d_ws, size_t ws_size,
                              hipStream_t stream) {
    const float* h      = (const float*)d_in[0];
    const float* V      = (const float*)d_in[1];
    const float* w_comp = (const float*)d_in[2];
    const float* loop_w = (const float*)d_in[3];
    const float* bias   = (const float*)d_in[4];
    const float* ffn_w  = (const float*)d_in[5];
    const float* ffn_b  = (const float*)d_in[6];
    const float* ln_g   = (const float*)d_in[7];
    const float* ln_b   = (const float*)d_in[8];
    const float* norm   = (const float*)d_in[9];
    const int*   src    = (const int*)d_in[10];
    const int*   dst    = (const int*)d_in[11];
    const int*   etype  = (const int*)d_in[12];
    float* out = (float*)d_out;

    if (ws_size < (size_t)WS_NEEDED) return;

    char* ws = (char*)d_ws;
    bf16*  Hr   = (bf16*)(ws + HR_OFF);
    uint2* recs = (uint2*)(ws + RECS_OFF);
    int*   base = (int*)(ws + BASE_OFF);
    int*   cur  = (int*)(ws + CUR_OFF);
    bf16*  WrT  = (bf16*)(ws + WRT_OFF);
    float* fwT  = (float*)(ws + FWT_OFF);

    // 1. weights prep + zero histogram
    k_prep<<<dim3((NREL * DIM * DIM + 255) / 256), dim3(256), 0, stream>>>(
        V, w_comp, ffn_w, WrT, fwT, cur);

    // 2-4. CSR build: histogram, scan, scatter
    k_hist<<<dim3((N_EDGES + 255) / 256), dim3(256), 0, stream>>>(dst, cur);
    k_scan<<<dim3(1), dim3(1024), 0, stream>>>(cur, base);
    k_scatter<<<dim3((N_EDGES + 255) / 256), dim3(256), 0, stream>>>(
        src, dst, etype, norm, cur, recs);

    // 5. Hr[r] = h @ W_r  (MFMA, 4 relations per block)
    k_gemm<<<dim3((N_NODES + 127) / 128, 2), dim3(256), 0, stream>>>(h, WrT, Hr);

    // 6. fused CSR gather + self-loop + relu + ffn + residual + layernorm
    k_final<<<dim3(2048), dim3(128), 0, stream>>>(
        h, Hr, recs, base, loop_w, bias, fwT, ffn_b, ln_g, ln_b, out);
}

// Round 5
// 216.607 us; speedup vs baseline: 3.8232x; 1.6735x over previous
//
#include <hip/hip_runtime.h>
#include <hip/hip_bf16.h>

#define N_NODES 50000
#define N_EDGES 400000
#define DIM     128
#define NREL    8
#define NBASES  4

typedef __hip_bfloat16 bf16;

typedef __bf16 bf16x8 __attribute__((ext_vector_type(8)));
typedef float  f32x4  __attribute__((ext_vector_type(4)));

union frag_u { bf16x8 v; bf16 e[8]; };
union pack4_u { unsigned long long ll; bf16 b[4]; };

// ---- workspace layout (bytes) ----
// Hr   bf16 [NREL][N_NODES][DIM] : 102,400,000
// recs uint2 [E]                 :   3,200,000  (key=(src<<3)|et, norm bits)
// base int  [N_NODES+1] (pad)    :     200,064
// cur  int  [N_NODES]   (pad)    :     200,064
// WrT  bf16 [NREL][DIM][DIM]     :     262,144  (WrT[r][o][i] = W_r[i][o])
// lwT  bf16 [DIM][DIM]           :      32,768  (lwT[o][i] = loop_w[i][o])
// fwTb bf16 [DIM][DIM]           :      32,768  (fwTb[o][i] = ffn_w[o][i])
#define HR_OFF    0LL
#define RECS_OFF  102400000LL
#define BASE_OFF  105600000LL
#define CUR_OFF   105800064LL
#define WRT_OFF   106000128LL
#define LWT_OFF   106262272LL
#define FWTB_OFF  106295040LL
#define WS_NEEDED 106327808LL

// ---------------------------------------------------------------------------
// K_prep: WrT, lwT, fwTb (bf16), zero histogram.
__global__ __launch_bounds__(256)
void k_prep(const float* __restrict__ V, const float* __restrict__ wc,
            const float* __restrict__ loop_w, const float* __restrict__ ffn_w,
            bf16* __restrict__ WrT, bf16* __restrict__ lwT,
            bf16* __restrict__ fwTb, int* __restrict__ cur) {
    int p = blockIdx.x * 256 + threadIdx.x;
    if (p < NREL * DIM * DIM) {
        int r = p >> 14;
        int rem = p & 16383;      // i*128+o
        int i = rem >> 7, o = rem & 127;
        float acc = 0.f;
#pragma unroll
        for (int b = 0; b < NBASES; ++b)
            acc += wc[r * NBASES + b] * V[b * DIM * DIM + rem];
        WrT[r * DIM * DIM + o * DIM + i] = __float2bfloat16(acc);
    }
    if (p < DIM * DIM) {
        int o = p >> 7, i = p & 127;
        lwT[p]  = __float2bfloat16(loop_w[i * DIM + o]);
        fwTb[p] = __float2bfloat16(ffn_w[p]);           // ffn_w[o][i]
    }
    if (p < N_NODES) cur[p] = 0;
}

// ---------------------------------------------------------------------------
// K_hist: cur[d] = in-degree histogram
__global__ __launch_bounds__(256)
void k_hist(const int* __restrict__ dst, int* __restrict__ cur) {
    int e = blockIdx.x * 256 + threadIdx.x;
    if (e < N_EDGES) atomicAdd(&cur[dst[e]], 1);
}

// ---------------------------------------------------------------------------
// K_scan: exclusive prefix sum of cur -> base; cur <- base.
// Single block, 1024 thr, 13 int4 (52 ints) per thread for load ILP.
#define SCAN_V 13
__global__ __launch_bounds__(1024)
void k_scan(int* __restrict__ cur, int* __restrict__ base) {
    __shared__ int wsum[16];
    const int t = threadIdx.x, lane = t & 63, wv = t >> 6;
    const int i0 = t * (SCAN_V * 4);
    int4 v[SCAN_V];
#pragma unroll
    for (int i = 0; i < SCAN_V; ++i) {
        int idx = i0 + i * 4;
        if (idx + 3 < N_NODES) v[i] = *(const int4*)(cur + idx);
        else {
            v[i].x = (idx + 0 < N_NODES) ? cur[idx + 0] : 0;
            v[i].y = (idx + 1 < N_NODES) ? cur[idx + 1] : 0;
            v[i].z = (idx + 2 < N_NODES) ? cur[idx + 2] : 0;
            v[i].w = (idx + 3 < N_NODES) ? cur[idx + 3] : 0;
        }
    }
    int s = 0;
#pragma unroll
    for (int i = 0; i < SCAN_V; ++i) s += v[i].x + v[i].y + v[i].z + v[i].w;
    int inc = s;
#pragma unroll
    for (int m = 1; m < 64; m <<= 1) {
        int u = __shfl_up(inc, m);
        if (lane >= m) inc += u;
    }
    if (lane == 63) wsum[wv] = inc;
    __syncthreads();
    if (t < 16) {
        int w = wsum[t];
        int winc = w;
#pragma unroll
        for (int m = 1; m < 16; m <<= 1) {
            int u = __shfl_up(winc, m);
            if (t >= m) winc += u;
        }
        wsum[t] = winc - w;
    }
    __syncthreads();
    int run = wsum[wv] + (inc - s);
#pragma unroll
    for (int i = 0; i < SCAN_V; ++i) {
        int idx = i0 + i * 4;
        if (idx + 3 < N_NODES) {
            int4 o;
            o.x = run; o.y = o.x + v[i].x; o.z = o.y + v[i].y; o.w = o.z + v[i].z;
            run = o.w + v[i].w;
            *(int4*)(base + idx) = o;
            *(int4*)(cur + idx) = o;
        } else {
            if (idx + 0 < N_NODES) { base[idx+0] = run; cur[idx+0] = run; run += v[i].x; }
            if (idx + 1 < N_NODES) { base[idx+1] = run; cur[idx+1] = run; run += v[i].y; }
            if (idx + 2 < N_NODES) { base[idx+2] = run; cur[idx+2] = run; run += v[i].z; }
            if (idx + 3 < N_NODES) { base[idx+3] = run; cur[idx+3] = run; run += v[i].w; }
        }
    }
    if (t == 1023) base[N_NODES] = run;
}

// ---------------------------------------------------------------------------
// K_scatter: bucket edges by dst.
__global__ __launch_bounds__(256)
void k_scatter(const int* __restrict__ src, const int* __restrict__ dst,
               const int* __restrict__ et, const float* __restrict__ norm,
               int* __restrict__ cur, uint2* __restrict__ recs) {
    int e = blockIdx.x * 256 + threadIdx.x;
    if (e >= N_EDGES) return;
    int d = dst[e];
    int pos = atomicAdd(&cur[d], 1);
    uint2 rc;
    rc.x = ((unsigned)src[e] << 3) | (unsigned)et[e];
    rc.y = __float_as_uint(norm[e]);
    recs[pos] = rc;
}

// ---------------------------------------------------------------------------
// K_gemm (MFMA): Hr[r] = bf16(h @ W_r), all 8 rels per block (h read once).
// LDS-staged epilogue -> fully coalesced 16B/lane Hr stores.
__global__ __launch_bounds__(256)
void k_gemm(const float* __restrict__ h, const bf16* __restrict__ WrT,
            bf16* __restrict__ Hr) {
    __shared__ __align__(16) char A_lds[128 * 256];     // 32 KB swizzled bf16
    __shared__ __align__(16) char ostage[4][8192];      // 8 KB per wave
    const int t   = threadIdx.x;
    const int wid = t >> 6;
    const int l   = t & 63;
    const int n0  = blockIdx.x * 128;

    // stage A: f32 -> bf16, swizzled
#pragma unroll
    for (int it = 0; it < 16; ++it) {
        int u = it * 256 + t;
        int row = u >> 5, c4 = u & 31;
        int gr = n0 + row;
        f32x4 v = (gr < N_NODES)
                      ? *(const f32x4*)(h + (long long)gr * DIM + c4 * 4)
                      : f32x4{0.f, 0.f, 0.f, 0.f};
        pack4_u p;
#pragma unroll
        for (int j = 0; j < 4; ++j) p.b[j] = __float2bfloat16(v[j]);
        int byte = row * 256 + c4 * 8;
        byte ^= (row & 7) << 4;
        *(unsigned long long*)(A_lds + byte) = p.ll;
    }
    __syncthreads();

    const int lrow = l & 15;
    const int kgrp = l >> 4;
    const int arow_base = wid * 32;
    char* os = ostage[wid];

#pragma unroll 1
    for (int rel = 0; rel < NREL; ++rel) {
        const bf16* Bsrc = WrT + rel * DIM * DIM;
        f32x4 acc[2][8];
#pragma unroll
        for (int mt = 0; mt < 2; ++mt)
#pragma unroll
            for (int nt = 0; nt < 8; ++nt)
                acc[mt][nt] = f32x4{0.f, 0.f, 0.f, 0.f};

#pragma unroll
        for (int ks = 0; ks < 4; ++ks) {
            frag_u a[2];
#pragma unroll
            for (int mt = 0; mt < 2; ++mt) {
                int arow = arow_base + mt * 16 + lrow;
                int byte = arow * 256 + ks * 64 + kgrp * 16;
                byte ^= (arow & 7) << 4;
                a[mt].v = *(const bf16x8*)(A_lds + byte);
            }
            frag_u b[8];
#pragma unroll
            for (int nt = 0; nt < 8; ++nt)
                b[nt].v = *(const bf16x8*)(Bsrc + (nt * 16 + lrow) * DIM +
                                           ks * 32 + kgrp * 8);
#pragma unroll
            for (int mt = 0; mt < 2; ++mt)
#pragma unroll
                for (int nt = 0; nt < 8; ++nt)
                    acc[mt][nt] = __builtin_amdgcn_mfma_f32_16x16x32_bf16(
                        b[nt].v, a[mt].v, acc[mt][nt], 0, 0, 0);
        }

        // stage C tile (32 rows x 256 B) into wave-private LDS, swizzled
#pragma unroll
        for (int mt = 0; mt < 2; ++mt) {
            int r = mt * 16 + lrow;
#pragma unroll
            for (int nt = 0; nt < 8; ++nt) {
                pack4_u p;
#pragma unroll
                for (int j = 0; j < 4; ++j)
                    p.b[j] = __float2bfloat16(acc[mt][nt][j]);
                int byte = r * 256 + (nt * 16 + kgrp * 4) * 2;
                byte ^= (r & 7) << 4;
                *(unsigned long long*)(os + byte) = p.ll;
            }
        }
        // read back row-major, store coalesced (4 rows / 1KB per instr)
#pragma unroll
        for (int it = 0; it < 8; ++it) {
            int flat = it * 1024 + l * 16;
            int r = flat >> 8, cbyte = flat & 255;
            int byte = (r * 256 + cbyte) ^ ((r & 7) << 4);
            bf16x8 vv = *(const bf16x8*)(os + byte);
            int grow = n0 + arow_base + r;
            if (grow < N_NODES)
                *(bf16x8*)((char*)(Hr + ((long long)rel * N_NODES + grow) * DIM) +
                           cbyte) = vv;
        }
    }
}

// ---------------------------------------------------------------------------
// K_final: 32 nodes/block, 256 thr (4 waves).
//   B: CSR gather (4-edge groups per wave, shfl-reduce) -> aggy (f32, swz LDS)
//   C: MFMA1 hn = relu(h@loop_w + agg + bias)  -> hnb (bf16, swz)
//   D: MFMA2 y = hn@ffn_w^T + ffn_b + h        -> aggy (reused)
//   E: LayerNorm -> out
__global__ __launch_bounds__(256)
void k_final(const float* __restrict__ h, const bf16* __restrict__ Hr,
             const uint2* __restrict__ recs, const int* __restrict__ base,
             const bf16* __restrict__ lwT, const float* __restrict__ bias,
             const bf16* __restrict__ fwTb, const float* __restrict__ ffn_b,
             const float* __restrict__ ln_g, const float* __restrict__ ln_b,
             float* __restrict__ out) {
    __shared__ __align__(16) char habf[32 * 256];   // 8 KB bf16 swz
    __shared__ __align__(16) char aggy[32 * 512];   // 16 KB f32 swz (agg, then y)
    __shared__ __align__(16) char hnb[32 * 256];    // 8 KB bf16 swz
    const int t = threadIdx.x, wv = t >> 6, l = t & 63;
    const int n0 = blockIdx.x * 32;

    // ---- A: load h -> habf (bf16, swizzled) ----
#pragma unroll
    for (int it = 0; it < 4; ++it) {
        int u = it * 256 + t;           // f32x4 units: 32 rows x 32
        int row = u >> 5, c4 = u & 31;
        int gr = n0 + row;
        f32x4 v = (gr < N_NODES)
                      ? *(const f32x4*)(h + (long long)gr * DIM + c4 * 4)
                      : f32x4{0.f, 0.f, 0.f, 0.f};
        pack4_u p;
#pragma unroll
        for (int j = 0; j < 4; ++j) p.b[j] = __float2bfloat16(v[j]);
        int byte = (row * 256 + c4 * 8) ^ ((row & 7) << 4);
        *(unsigned long long*)(habf + byte) = p.ll;
    }

    // ---- B: CSR gather. wave wv: nodes 8wv..8wv+7; 16-lane group g owns
    //         every-4th edge; cross-group shfl reduce. ----
    const int g = l >> 4, c = l & 15;
#pragma unroll 1
    for (int jj = 0; jj < 8; ++jj) {
        const int row = wv * 8 + jj;
        const int n = n0 + row;
        float acc[8];
#pragma unroll
        for (int q = 0; q < 8; ++q) acc[q] = 0.f;
        if (n < N_NODES) {
            const int b1 = base[n + 1];
            for (int e = base[n] + g; e < b1; e += 4) {
                uint2 rc = recs[e];
                float w = __uint_as_float(rc.y);
                frag_u f;
                f.v = *((const bf16x8*)(Hr +
                        ((long long)(rc.x & 7u) * N_NODES + (rc.x >> 3)) * DIM) + c);
#pragma unroll
                for (int q = 0; q < 8; ++q)
                    acc[q] = fmaf(__bfloat162float(f.e[q]), w, acc[q]);
            }
        }
#pragma unroll
        for (int q = 0; q < 8; ++q) {
            acc[q] += __shfl_xor(acc[q], 16);
            acc[q] += __shfl_xor(acc[q], 32);
        }
        if (g == 0) {
            const int x = (row & 7) << 4;
            f32x4 lo{acc[0], acc[1], acc[2], acc[3]};
            f32x4 hi{acc[4], acc[5], acc[6], acc[7]};
            *(f32x4*)(aggy + ((row * 512 + c * 32) ^ x)) = lo;
            *(f32x4*)(aggy + ((row * 512 + c * 32 + 16) ^ x)) = hi;
        }
    }
    __syncthreads();

    // ---- C: MFMA1: hn = relu(h @ loop_w + agg + bias) ----
    const int lrow = l & 15, kgrp = l >> 4;
    const int rw = (wv & 1) * 16, cb = (wv >> 1) * 64;
    const int arow = rw + lrow;
    {
        f32x4 acc1[4];
#pragma unroll
        for (int nt = 0; nt < 4; ++nt) acc1[nt] = f32x4{0.f, 0.f, 0.f, 0.f};
#pragma unroll
        for (int ks = 0; ks < 4; ++ks) {
            frag_u a;
            int abyte = (arow * 256 + ks * 64 + kgrp * 16) ^ ((arow & 7) << 4);
            a.v = *(const bf16x8*)(habf + abyte);
#pragma unroll
            for (int nt = 0; nt < 4; ++nt) {
                frag_u b;
                b.v = *(const bf16x8*)(lwT + (cb + nt * 16 + lrow) * DIM +
                                       ks * 32 + kgrp * 8);
                acc1[nt] = __builtin_amdgcn_mfma_f32_16x16x32_bf16(
                    b.v, a.v, acc1[nt], 0, 0, 0);
            }
        }
        const int x = (arow & 7) << 4;
#pragma unroll
        for (int nt = 0; nt < 4; ++nt) {
            int col = cb + nt * 16 + kgrp * 4;
            f32x4 ag = *(const f32x4*)(aggy + ((arow * 512 + col * 4) ^ x));
            f32x4 bi = *(const f32x4*)(bias + col);
            pack4_u p;
#pragma unroll
            for (int j = 0; j < 4; ++j)
                p.b[j] = __float2bfloat16(fmaxf(acc1[nt][j] + ag[j] + bi[j], 0.f));
            *(unsigned long long*)(hnb + ((arow * 256 + col * 2) ^ x)) = p.ll;
        }
    }
    __syncthreads();

    // ---- D: MFMA2: y = hn @ ffn_w^T + ffn_b + h ----
    {
        f32x4 acc2[4];
#pragma unroll
        for (int nt = 0; nt < 4; ++nt) acc2[nt] = f32x4{0.f, 0.f, 0.f, 0.f};
#pragma unroll
        for (int ks = 0; ks < 4; ++ks) {
            frag_u a;
            int abyte = (arow * 256 + ks * 64 + kgrp * 16) ^ ((arow & 7) << 4);
            a.v = *(const bf16x8*)(hnb + abyte);
#pragma unroll
            for (int nt = 0; nt < 4; ++nt) {
                frag_u b;
                b.v = *(const bf16x8*)(fwTb + (cb + nt * 16 + lrow) * DIM +
                                       ks * 32 + kgrp * 8);
                acc2[nt] = __builtin_amdgcn_mfma_f32_16x16x32_bf16(
                    b.v, a.v, acc2[nt], 0, 0, 0);
            }
        }
        const int x = (arow & 7) << 4;
#pragma unroll
        for (int nt = 0; nt < 4; ++nt) {
            int col = cb + nt * 16 + kgrp * 4;
            f32x4 fb = *(const f32x4*)(ffn_b + col);
            pack4_u hp;
            hp.ll = *(const unsigned long long*)(habf + ((arow * 256 + col * 2) ^ x));
            f32x4 y;
#pragma unroll
            for (int j = 0; j < 4; ++j)
                y[j] = acc2[nt][j] + fb[j] + __bfloat162float(hp.b[j]);
            *(f32x4*)(aggy + ((arow * 512 + col * 4) ^ x)) = y;
        }
    }
    __syncthreads();

    // ---- E: LayerNorm. wave wv: rows 8wv..8wv+7 ----
    // FIX vs R4: read the swizzled ADDRESS (pre-byte l*8, addr = pre^x);
    // the column is the PRE-swizzle index 2l, not the swizzled one.
#pragma unroll 1
    for (int jr = 0; jr < 8; ++jr) {
        const int row = wv * 8 + jr;
        const int n = n0 + row;
        const int x = (row & 7) << 4;
        float2 yv = *(const float2*)(aggy + row * 512 + ((l * 8) ^ x));
        const int col = l * 2;
        float s = yv.x + yv.y, s2 = yv.x * yv.x + yv.y * yv.y;
#pragma unroll
        for (int m = 1; m < 64; m <<= 1) {
            s  += __shfl_xor(s, m);
            s2 += __shfl_xor(s2, m);
        }
        if (n < N_NODES) {
            float mu  = s * (1.f / DIM);
            float var = s2 * (1.f / DIM) - mu * mu;
            float inv = rsqrtf(var + 1e-8f);
            float2 gv = *(const float2*)(ln_g + col);
            float2 bv = *(const float2*)(ln_b + col);
            float2 o2{(yv.x - mu) * inv * gv.x + bv.x,
                      (yv.y - mu) * inv * gv.y + bv.y};
            *(float2*)(out + (long long)n * DIM + col) = o2;
        }
    }
}

// ---------------------------------------------------------------------------
extern "C" void kernel_launch(void* const* d_in, const int* in_sizes, int n_in,
                              void* d_out, int out_size, void* d_ws, size_t ws_size,
                              hipStream_t stream) {
    const float* h      = (const float*)d_in[0];
    const float* V      = (const float*)d_in[1];
    const float* w_comp = (const float*)d_in[2];
    const float* loop_w = (const float*)d_in[3];
    const float* bias   = (const float*)d_in[4];
    const float* ffn_w  = (const float*)d_in[5];
    const float* ffn_b  = (const float*)d_in[6];
    const float* ln_g   = (const float*)d_in[7];
    const float* ln_b   = (const float*)d_in[8];
    const float* norm   = (const float*)d_in[9];
    const int*   src    = (const int*)d_in[10];
    const int*   dst    = (const int*)d_in[11];
    const int*   etype  = (const int*)d_in[12];
    float* out = (float*)d_out;

    if (ws_size < (size_t)WS_NEEDED) return;

    char* ws = (char*)d_ws;
    bf16*  Hr   = (bf16*)(ws + HR_OFF);
    uint2* recs = (uint2*)(ws + RECS_OFF);
    int*   base = (int*)(ws + BASE_OFF);
    int*   cur  = (int*)(ws + CUR_OFF);
    bf16*  WrT  = (bf16*)(ws + WRT_OFF);
    bf16*  lwT  = (bf16*)(ws + LWT_OFF);
    bf16*  fwTb = (bf16*)(ws + FWTB_OFF);

    k_prep<<<dim3((NREL * DIM * DIM + 255) / 256), dim3(256), 0, stream>>>(
        V, w_comp, loop_w, ffn_w, WrT, lwT, fwTb, cur);

    k_hist<<<dim3((N_EDGES + 255) / 256), dim3(256), 0, stream>>>(dst, cur);
    k_scan<<<dim3(1), dim3(1024), 0, stream>>>(cur, base);
    k_scatter<<<dim3((N_EDGES + 255) / 256), dim3(256), 0, stream>>>(
        src, dst, etype, norm, cur, recs);

    k_gemm<<<dim3((N_NODES + 127) / 128), dim3(256), 0, stream>>>(h, WrT, Hr);

    k_final<<<dim3((N_NODES + 31) / 32), dim3(256), 0, stream>>>(
        h, Hr, recs, base, lwT, bias, fwTb, ffn_b, ln_g, ln_b, out);
}

// Round 6
// 212.959 us; speedup vs baseline: 3.8887x; 1.0171x over previous
//
#include <hip/hip_runtime.h>
#include <hip/hip_bf16.h>

#define N_NODES 50000
#define N_EDGES 400000
#define DIM     128
#define NREL    8
#define NBASES  4
#define PLANE   ((long long)N_NODES * DIM)

typedef __hip_bfloat16 bf16;

typedef __bf16 bf16x8 __attribute__((ext_vector_type(8)));
typedef float  f32x4  __attribute__((ext_vector_type(4)));

union frag_u { bf16x8 v; bf16 e[8]; };
union pack4_u { unsigned long long ll; bf16 b[4]; };

// ---- workspace layout (bytes) ----
// Hb   bf16 [NB][N][D] : 51,200,000   (basis-projected nodes)
// hb16 bf16 [N][D]     : 12,800,000   (h pre-converted to bf16)
// rsrc int  [E]        :  1,600,000
// rc4  f32x4[E]        :  6,400,000   (per-edge coef_b * norm, f32)
// base int  [N+1] pad  :    200,064
// cur  int  [N]   pad  :    200,064
// VbT  bf16 [NB][D][D] :    131,072   (VbT[b][o][i] = V[b][i][o])
// lwT  bf16 [D][D]     :     32,768
// fwTb bf16 [D][D]     :     32,768
#define HB_OFF    0LL
#define HB16_OFF  51200000LL
#define RSRC_OFF  64000000LL
#define RC_OFF    65600000LL
#define BASE_OFF  72000000LL
#define CUR_OFF   72200064LL
#define VBT_OFF   72400128LL
#define LWT_OFF   72531200LL
#define FWT_OFF   72563968LL
#define WS_NEEDED 72596736LL

// swizzles: full-row entropy (fix for R5's 8-way conflicts)
__device__ __forceinline__ int swzb(int row) { return (row & 15) << 4; }  // 256B rows
__device__ __forceinline__ int swzy(int row) { return (row & 31) << 4; }  // 512B rows

// ---------------------------------------------------------------------------
// K_prep (grid 3125x256 = 800000 thr): h->bf16, in-degree hist, VbT/lwT/fwTb.
// cur must be zeroed (hipMemsetAsync) before this kernel.
__global__ __launch_bounds__(256)
void k_prep(const float* __restrict__ h, const float* __restrict__ V,
            const float* __restrict__ loop_w, const float* __restrict__ ffn_w,
            const int* __restrict__ dst,
            bf16* __restrict__ hb, bf16* __restrict__ VbT,
            bf16* __restrict__ lwT, bf16* __restrict__ fwTb,
            int* __restrict__ cur) {
    int p = blockIdx.x * 256 + threadIdx.x;
    if (p < N_NODES * DIM / 8) {
        const float* s = h + (long long)p * 8;
        f32x4 lo = *(const f32x4*)s, hi = *(const f32x4*)(s + 4);
        frag_u o;
#pragma unroll
        for (int j = 0; j < 4; ++j) {
            o.e[j]     = __float2bfloat16(lo[j]);
            o.e[4 + j] = __float2bfloat16(hi[j]);
        }
        *(bf16x8*)(hb + (long long)p * 8) = o.v;
    }
    if (p < N_EDGES) atomicAdd(&cur[dst[p]], 1);
    if (p < NBASES * DIM * DIM) {
        int b = p >> 14, rem = p & 16383, i = rem >> 7, o = rem & 127;
        VbT[(b << 14) + o * DIM + i] = __float2bfloat16(V[p]);
    }
    if (p < DIM * DIM) {
        lwT[p]  = __float2bfloat16(loop_w[(p & 127) * DIM + (p >> 7)]);
        fwTb[p] = __float2bfloat16(ffn_w[p]);
    }
}

// ---------------------------------------------------------------------------
// K_scan: exclusive prefix sum of cur -> base; cur <- base. 1 block.
#define SCAN_V 13
__global__ __launch_bounds__(1024)
void k_scan(int* __restrict__ cur, int* __restrict__ base) {
    __shared__ int wsum[16];
    const int t = threadIdx.x, lane = t & 63, wv = t >> 6;
    const int i0 = t * (SCAN_V * 4);
    int4 v[SCAN_V];
#pragma unroll
    for (int i = 0; i < SCAN_V; ++i) {
        int idx = i0 + i * 4;
        if (idx + 3 < N_NODES) v[i] = *(const int4*)(cur + idx);
        else {
            v[i].x = (idx + 0 < N_NODES) ? cur[idx + 0] : 0;
            v[i].y = (idx + 1 < N_NODES) ? cur[idx + 1] : 0;
            v[i].z = (idx + 2 < N_NODES) ? cur[idx + 2] : 0;
            v[i].w = (idx + 3 < N_NODES) ? cur[idx + 3] : 0;
        }
    }
    int s = 0;
#pragma unroll
    for (int i = 0; i < SCAN_V; ++i) s += v[i].x + v[i].y + v[i].z + v[i].w;
    int inc = s;
#pragma unroll
    for (int m = 1; m < 64; m <<= 1) {
        int u = __shfl_up(inc, m);
        if (lane >= m) inc += u;
    }
    if (lane == 63) wsum[wv] = inc;
    __syncthreads();
    if (t < 16) {
        int w = wsum[t];
        int winc = w;
#pragma unroll
        for (int m = 1; m < 16; m <<= 1) {
            int u = __shfl_up(winc, m);
            if (t >= m) winc += u;
        }
        wsum[t] = winc - w;
    }
    __syncthreads();
    int run = wsum[wv] + (inc - s);
#pragma unroll
    for (int i = 0; i < SCAN_V; ++i) {
        int idx = i0 + i * 4;
        if (idx + 3 < N_NODES) {
            int4 o;
            o.x = run; o.y = o.x + v[i].x; o.z = o.y + v[i].y; o.w = o.z + v[i].z;
            run = o.w + v[i].w;
            *(int4*)(base + idx) = o;
            *(int4*)(cur + idx) = o;
        } else {
            if (idx + 0 < N_NODES) { base[idx+0] = run; cur[idx+0] = run; run += v[i].x; }
            if (idx + 1 < N_NODES) { base[idx+1] = run; cur[idx+1] = run; run += v[i].y; }
            if (idx + 2 < N_NODES) { base[idx+2] = run; cur[idx+2] = run; run += v[i].z; }
            if (idx + 3 < N_NODES) { base[idx+3] = run; cur[idx+3] = run; run += v[i].w; }
        }
    }
    if (t == 1023) base[N_NODES] = run;
}

// ---------------------------------------------------------------------------
// K_scatter: bucket edges by dst; store src + f32 coef vector (wc[et]*norm).
__global__ __launch_bounds__(256)
void k_scatter(const int* __restrict__ src, const int* __restrict__ dst,
               const int* __restrict__ et, const float* __restrict__ norm,
               const float* __restrict__ wc,
               int* __restrict__ cur, int* __restrict__ rsrc,
               f32x4* __restrict__ rc4) {
    int e = blockIdx.x * 256 + threadIdx.x;
    if (e >= N_EDGES) return;
    int d = dst[e];
    int pos = atomicAdd(&cur[d], 1);
    int r = et[e];
    float nm = norm[e];
    f32x4 c = *(const f32x4*)(wc + r * NBASES);
#pragma unroll
    for (int b = 0; b < 4; ++b) c[b] *= nm;
    rsrc[pos] = src[e];
    rc4[pos]  = c;
}

// ---------------------------------------------------------------------------
// K_gemm v3 (MFMA): Hb[b] = bf16(h @ V_b). Block = 128 rows x 1 base.
// No A-staging LDS: A fragments loaded directly from pre-converted hb16.
// Grid (391, 4) = 1564 blocks; LDS 32 KB (epilogue stage) -> 5 blocks/CU.
__global__ __launch_bounds__(256)
void k_gemm(const bf16* __restrict__ hb, const bf16* __restrict__ VbT,
            bf16* __restrict__ Hb) {
    __shared__ __align__(16) char ostage[4][8192];
    const int t   = threadIdx.x;
    const int wid = t >> 6;
    const int l   = t & 63;
    const int n0  = blockIdx.x * 128;
    const int bb  = blockIdx.y;

    const int lrow = l & 15;
    const int kgrp = l >> 4;
    const bf16* Bsrc = VbT + (bb << 14);

    f32x4 acc[2][8];
#pragma unroll
    for (int mt = 0; mt < 2; ++mt)
#pragma unroll
        for (int nt = 0; nt < 8; ++nt)
            acc[mt][nt] = f32x4{0.f, 0.f, 0.f, 0.f};

#pragma unroll
    for (int ks = 0; ks < 4; ++ks) {
        frag_u a[2];
#pragma unroll
        for (int mt = 0; mt < 2; ++mt) {
            int row = n0 + wid * 32 + mt * 16 + lrow;
            row = row < N_NODES ? row : N_NODES - 1;
            a[mt].v = *(const bf16x8*)(hb + (long long)row * DIM + ks * 32 + kgrp * 8);
        }
        frag_u b[8];
#pragma unroll
        for (int nt = 0; nt < 8; ++nt)
            b[nt].v = *(const bf16x8*)(Bsrc + (nt * 16 + lrow) * DIM +
                                       ks * 32 + kgrp * 8);
#pragma unroll
        for (int mt = 0; mt < 2; ++mt)
#pragma unroll
            for (int nt = 0; nt < 8; ++nt)
                acc[mt][nt] = __builtin_amdgcn_mfma_f32_16x16x32_bf16(
                    b[nt].v, a[mt].v, acc[mt][nt], 0, 0, 0);
    }

    // epilogue: stage wave's 32x128 tile in LDS (swizzled), read back row-major
    char* os = ostage[wid];
#pragma unroll
    for (int mt = 0; mt < 2; ++mt) {
        int r = mt * 16 + lrow;
#pragma unroll
        for (int nt = 0; nt < 8; ++nt) {
            pack4_u p;
#pragma unroll
            for (int j = 0; j < 4; ++j)
                p.b[j] = __float2bfloat16(acc[mt][nt][j]);
            int byte = (r * 256 + (nt * 16 + kgrp * 4) * 2) ^ swzb(r);
            *(unsigned long long*)(os + byte) = p.ll;
        }
    }
    __builtin_amdgcn_s_waitcnt(0);   // lgkm drain within wave
#pragma unroll
    for (int it = 0; it < 8; ++it) {
        int flat = it * 1024 + l * 16;
        int r = flat >> 8, cbyte = flat & 255;
        int byte = (r * 256 + cbyte) ^ swzb(r);
        bf16x8 vv = *(const bf16x8*)(os + byte);
        int grow = n0 + wid * 32 + r;
        if (grow < N_NODES)
            *(bf16x8*)((char*)(Hb + (long long)bb * PLANE +
                               (long long)grow * DIM) + cbyte) = vv;
    }
}

// ---------------------------------------------------------------------------
// K_final: 32 nodes/block, 256 thr (4 waves).
//   B: CSR gather, 4 basis planes per edge (4 indep loads) -> aggy (f32 swz)
//   C: MFMA1 hn = relu(h@loop_w + agg + bias)  -> hnb (bf16 swz)
//   D: MFMA2 y = hn@ffn_w^T + ffn_b + h        -> aggy (reused)
//   E: LayerNorm -> out
__global__ __launch_bounds__(256)
void k_final(const float* __restrict__ h, const bf16* __restrict__ Hb,
             const int* __restrict__ rsrc, const f32x4* __restrict__ rc4,
             const int* __restrict__ base,
             const bf16* __restrict__ lwT, const float* __restrict__ bias,
             const bf16* __restrict__ fwTb, const float* __restrict__ ffn_b,
             const float* __restrict__ ln_g, const float* __restrict__ ln_b,
             float* __restrict__ out) {
    __shared__ __align__(16) char habf[32 * 256];   // 8 KB bf16 swz
    __shared__ __align__(16) char aggy[32 * 512];   // 16 KB f32 swz
    __shared__ __align__(16) char hnb[32 * 256];    // 8 KB bf16 swz
    const int t = threadIdx.x, wv = t >> 6, l = t & 63;
    const int n0 = blockIdx.x * 32;

    // ---- A: load h -> habf (bf16, swizzled) ----
#pragma unroll
    for (int it = 0; it < 4; ++it) {
        int u = it * 256 + t;
        int row = u >> 5, c4 = u & 31;
        int gr = n0 + row;
        f32x4 v = (gr < N_NODES)
                      ? *(const f32x4*)(h + (long long)gr * DIM + c4 * 4)
                      : f32x4{0.f, 0.f, 0.f, 0.f};
        pack4_u p;
#pragma unroll
        for (int j = 0; j < 4; ++j) p.b[j] = __float2bfloat16(v[j]);
        int byte = (row * 256 + c4 * 8) ^ swzb(row);
        *(unsigned long long*)(habf + byte) = p.ll;
    }

    // ---- B: CSR gather, 4 planes/edge. wave wv: nodes 8wv..8wv+7;
    //         16-lane group g owns every-4th edge; shfl reduce. ----
    const int g = l >> 4, c = l & 15;
#pragma unroll 1
    for (int jj = 0; jj < 8; ++jj) {
        const int row = wv * 8 + jj;
        const int n = n0 + row;
        float acc[8];
#pragma unroll
        for (int q = 0; q < 8; ++q) acc[q] = 0.f;
        if (n < N_NODES) {
            const int b1 = base[n + 1];
            for (int e = base[n] + g; e < b1; e += 4) {
                const int s = rsrc[e];
                const f32x4 cf = rc4[e];
                const bf16* p0 = Hb + (long long)s * DIM + c * 8;
                frag_u f0, f1, f2, f3;
                f0.v = *(const bf16x8*)(p0);
                f1.v = *(const bf16x8*)(p0 + PLANE);
                f2.v = *(const bf16x8*)(p0 + 2 * PLANE);
                f3.v = *(const bf16x8*)(p0 + 3 * PLANE);
#pragma unroll
                for (int q = 0; q < 8; ++q) {
                    float m = cf[0] * __bfloat162float(f0.e[q]);
                    m = fmaf(cf[1], __bfloat162float(f1.e[q]), m);
                    m = fmaf(cf[2], __bfloat162float(f2.e[q]), m);
                    m = fmaf(cf[3], __bfloat162float(f3.e[q]), m);
                    acc[q] += m;
                }
            }
        }
#pragma unroll
        for (int q = 0; q < 8; ++q) {
            acc[q] += __shfl_xor(acc[q], 16);
            acc[q] += __shfl_xor(acc[q], 32);
        }
        if (g == 0) {
            const int x = swzy(row);
            f32x4 lo{acc[0], acc[1], acc[2], acc[3]};
            f32x4 hi{acc[4], acc[5], acc[6], acc[7]};
            *(f32x4*)(aggy + row * 512 + ((c * 32) ^ x)) = lo;
            *(f32x4*)(aggy + row * 512 + ((c * 32 + 16) ^ x)) = hi;
        }
    }
    __syncthreads();

    // ---- C: MFMA1: hn = relu(h @ loop_w + agg + bias) ----
    const int lrow = l & 15, kgrp = l >> 4;
    const int rw = (wv & 1) * 16, cb = (wv >> 1) * 64;
    const int arow = rw + lrow;
    {
        f32x4 acc1[4];
#pragma unroll
        for (int nt = 0; nt < 4; ++nt) acc1[nt] = f32x4{0.f, 0.f, 0.f, 0.f};
#pragma unroll
        for (int ks = 0; ks < 4; ++ks) {
            frag_u a;
            int abyte = (arow * 256 + ks * 64 + kgrp * 16) ^ swzb(arow);
            a.v = *(const bf16x8*)(habf + abyte);
#pragma unroll
            for (int nt = 0; nt < 4; ++nt) {
                frag_u b;
                b.v = *(const bf16x8*)(lwT + (cb + nt * 16 + lrow) * DIM +
                                       ks * 32 + kgrp * 8);
                acc1[nt] = __builtin_amdgcn_mfma_f32_16x16x32_bf16(
                    b.v, a.v, acc1[nt], 0, 0, 0);
            }
        }
        const int xb = swzb(arow), xy = swzy(arow);
#pragma unroll
        for (int nt = 0; nt < 4; ++nt) {
            int col = cb + nt * 16 + kgrp * 4;
            f32x4 ag = *(const f32x4*)(aggy + arow * 512 + ((col * 4) ^ xy));
            f32x4 bi = *(const f32x4*)(bias + col);
            pack4_u p;
#pragma unroll
            for (int j = 0; j < 4; ++j)
                p.b[j] = __float2bfloat16(fmaxf(acc1[nt][j] + ag[j] + bi[j], 0.f));
            *(unsigned long long*)(hnb + ((arow * 256 + col * 2) ^ xb)) = p.ll;
        }
    }
    __syncthreads();

    // ---- D: MFMA2: y = hn @ ffn_w^T + ffn_b + h ----
    {
        f32x4 acc2[4];
#pragma unroll
        for (int nt = 0; nt < 4; ++nt) acc2[nt] = f32x4{0.f, 0.f, 0.f, 0.f};
#pragma unroll
        for (int ks = 0; ks < 4; ++ks) {
            frag_u a;
            int abyte = (arow * 256 + ks * 64 + kgrp * 16) ^ swzb(arow);
            a.v = *(const bf16x8*)(hnb + abyte);
#pragma unroll
            for (int nt = 0; nt < 4; ++nt) {
                frag_u b;
                b.v = *(const bf16x8*)(fwTb + (cb + nt * 16 + lrow) * DIM +
                                       ks * 32 + kgrp * 8);
                acc2[nt] = __builtin_amdgcn_mfma_f32_16x16x32_bf16(
                    b.v, a.v, acc2[nt], 0, 0, 0);
            }
        }
        const int xb = swzb(arow), xy = swzy(arow);
#pragma unroll
        for (int nt = 0; nt < 4; ++nt) {
            int col = cb + nt * 16 + kgrp * 4;
            f32x4 fb = *(const f32x4*)(ffn_b + col);
            pack4_u hp;
            hp.ll = *(const unsigned long long*)(habf + ((arow * 256 + col * 2) ^ xb));
            f32x4 y;
#pragma unroll
            for (int j = 0; j < 4; ++j)
                y[j] = acc2[nt][j] + fb[j] + __bfloat162float(hp.b[j]);
            *(f32x4*)(aggy + arow * 512 + ((col * 4) ^ xy)) = y;
        }
    }
    __syncthreads();

    // ---- E: LayerNorm. Read swizzled ADDRESS; column is PRE-swizzle 2l. ----
#pragma unroll 1
    for (int jr = 0; jr < 8; ++jr) {
        const int row = wv * 8 + jr;
        const int n = n0 + row;
        const int x = swzy(row);
        float2 yv = *(const float2*)(aggy + row * 512 + ((l * 8) ^ x));
        const int col = l * 2;
        float s = yv.x + yv.y, s2 = yv.x * yv.x + yv.y * yv.y;
#pragma unroll
        for (int m = 1; m < 64; m <<= 1) {
            s  += __shfl_xor(s, m);
            s2 += __shfl_xor(s2, m);
        }
        if (n < N_NODES) {
            float mu  = s * (1.f / DIM);
            float var = s2 * (1.f / DIM) - mu * mu;
            float inv = rsqrtf(var + 1e-8f);
            float2 gv = *(const float2*)(ln_g + col);
            float2 bv = *(const float2*)(ln_b + col);
            float2 o2{(yv.x - mu) * inv * gv.x + bv.x,
                      (yv.y - mu) * inv * gv.y + bv.y};
            *(float2*)(out + (long long)n * DIM + col) = o2;
        }
    }
}

// ---------------------------------------------------------------------------
extern "C" void kernel_launch(void* const* d_in, const int* in_sizes, int n_in,
                              void* d_out, int out_size, void* d_ws, size_t ws_size,
                              hipStream_t stream) {
    const float* h      = (const float*)d_in[0];
    const float* V      = (const float*)d_in[1];
    const float* w_comp = (const float*)d_in[2];
    const float* loop_w = (const float*)d_in[3];
    const float* bias   = (const float*)d_in[4];
    const float* ffn_w  = (const float*)d_in[5];
    const float* ffn_b  = (const float*)d_in[6];
    const float* ln_g   = (const float*)d_in[7];
    const float* ln_b   = (const float*)d_in[8];
    const float* norm   = (const float*)d_in[9];
    const int*   src    = (const int*)d_in[10];
    const int*   dst    = (const int*)d_in[11];
    const int*   etype  = (const int*)d_in[12];
    float* out = (float*)d_out;

    if (ws_size < (size_t)WS_NEEDED) return;

    char* ws = (char*)d_ws;
    bf16*  Hb   = (bf16*)(ws + HB_OFF);
    bf16*  hb16 = (bf16*)(ws + HB16_OFF);
    int*   rsrc = (int*)(ws + RSRC_OFF);
    f32x4* rc4  = (f32x4*)(ws + RC_OFF);
    int*   base = (int*)(ws + BASE_OFF);
    int*   cur  = (int*)(ws + CUR_OFF);
    bf16*  VbT  = (bf16*)(ws + VBT_OFF);
    bf16*  lwT  = (bf16*)(ws + LWT_OFF);
    bf16*  fwTb = (bf16*)(ws + FWT_OFF);

    hipMemsetAsync(cur, 0, N_NODES * sizeof(int), stream);

    // h->bf16 + histogram + VbT/lwT/fwTb
    k_prep<<<dim3(3125), dim3(256), 0, stream>>>(
        h, V, loop_w, ffn_w, dst, hb16, VbT, lwT, fwTb, cur);

    k_scan<<<dim3(1), dim3(1024), 0, stream>>>(cur, base);
    k_scatter<<<dim3((N_EDGES + 255) / 256), dim3(256), 0, stream>>>(
        src, dst, etype, norm, w_comp, cur, rsrc, rc4);

    // Hb[b] = h @ V_b  (MFMA, 1 base per block)
    k_gemm<<<dim3((N_NODES + 127) / 128, NBASES), dim3(256), 0, stream>>>(
        hb16, VbT, Hb);

    // fused CSR gather (4 planes) + self-loop + relu + ffn + residual + LN
    k_final<<<dim3((N_NODES + 31) / 32), dim3(256), 0, stream>>>(
        h, Hb, rsrc, rc4, base, lwT, bias, fwTb, ffn_b, ln_g, ln_b, out);
}